// Round 12
// baseline (52.151 us; speedup 1.0000x reference)
//
#include <hip/hip_runtime.h>
#include <math.h>

typedef __attribute__((ext_vector_type(8))) short bf16x8;
typedef __attribute__((ext_vector_type(8))) unsigned short u16x8;
typedef __attribute__((ext_vector_type(4))) float f32x4;
typedef __attribute__((ext_vector_type(4))) unsigned int u32x4;

#define B_ 4
#define L_ 2048
#define S_ 2048
#define H_ 8
#define E_ 64
#define D_ 64
#define NT_ 32
#define TILE_BYTES 16384
#define TILES_BYTES ((size_t)B_ * H_ * NT_ * TILE_BYTES)       // 16 MB tile images
#define P1_OFF  TILES_BYTES                                     // 8 MB bf16 partial (chunk 1)
#define L0_OFF  (TILES_BYTES + (size_t)12 * 1024 * 1024)        // 256 KB l (chunk 0)
#define L1_OFF  (L0_OFF + 262144)                               // 256 KB l (chunk 1)
#define WS_NEEDED   TILES_BYTES
#define WS2_NEEDED  (L1_OFF + 262144)
#define SCL (0.125f * 1.44269504088896f)   // 1/sqrt(E) * log2(e)

__device__ __forceinline__ unsigned short f2bf(float x) {
    unsigned int u = __builtin_bit_cast(unsigned int, x);
    u += 0x7fffu + ((u >> 16) & 1u);
    return (unsigned short)(u >> 16);
}
// kv-row permute so S^T C-fragment layout == PV A-operand layout (verified rounds 1-11)
__device__ __forceinline__ int rho(int r) {
    return (r & 32) | (((r >> 2) & 1) << 4) | (((r >> 3) & 3) << 2) | (r & 3);
}
__device__ __forceinline__ void gload16(const void* g, void* l) {
    __builtin_amdgcn_global_load_lds((const __attribute__((address_space(1))) unsigned int*)g,
                                     (__attribute__((address_space(3))) unsigned int*)l, 16, 0, 0);
}

// ---------------- prep: K -> bf16 tile image, V -> V^T image; XCD-aligned to consumer ----------------
__global__ __launch_bounds__(256) void prep_kv(const float* __restrict__ K,
                                               const float* __restrict__ V,
                                               unsigned short* __restrict__ ws)
{
    __shared__ __align__(16) unsigned short vt[64][80];
    const int tid = threadIdx.x;
    const int bid = blockIdx.x;
    const int kt  = bid >> 5;
    const int bh  = (((bid >> 3) & 3) << 3) | (bid & 7);      // bid%8 == bh%8
    const int b   = bh >> 3, h = bh & 7;
    const int s0  = kt * 64;
    const int r   = tid >> 2;
    const int e0  = (tid & 3) * 16;

    const float* krow = K + (((size_t)(b * S_ + s0 + r)) * H_ + h) * E_ + e0;
    const float* vrow = V + (((size_t)(b * S_ + s0 + r)) * H_ + h) * D_ + e0;
    char* tile = (char*)(ws) + ((size_t)(bh * NT_ + kt) * TILE_BYTES);

    unsigned short kb[16];
    #pragma unroll
    for (int i = 0; i < 4; ++i) {
        f32x4 k4 = *(const f32x4*)(krow + i * 4);
        #pragma unroll
        for (int jq = 0; jq < 4; ++jq) kb[i * 4 + jq] = f2bf(k4[jq]);
    }
    {
        const int rr = rho(r);
        const int m  = (rr & 7) << 4;
        char* kbase = tile + rr * 128;
        u32x4 lo, hi;
        #pragma unroll
        for (int jq = 0; jq < 4; ++jq) {
            lo[jq] = (unsigned)kb[2 * jq] | ((unsigned)kb[2 * jq + 1] << 16);
            hi[jq] = (unsigned)kb[8 + 2 * jq] | ((unsigned)kb[9 + 2 * jq] << 16);
        }
        *(u32x4*)(kbase + ((2 * e0) ^ m))      = lo;
        *(u32x4*)(kbase + ((2 * e0 + 16) ^ m)) = hi;
    }
    #pragma unroll
    for (int i = 0; i < 4; ++i) {
        f32x4 v4 = *(const f32x4*)(vrow + i * 4);
        #pragma unroll
        for (int jq = 0; jq < 4; ++jq) vt[e0 + i * 4 + jq][r] = f2bf(v4[jq]);
    }
    __syncthreads();
    {
        const int d  = tid >> 2;
        const int c0 = (tid & 3) * 16;
        const int m  = (d & 7) << 4;
        char* vbase = tile + 8192 + d * 128;
        u32x4 lo = *(const u32x4*)&vt[d][c0];
        u32x4 hi = *(const u32x4*)&vt[d][c0 + 8];
        *(u32x4*)(vbase + ((2 * c0) ^ m))      = lo;
        *(u32x4*)(vbase + ((2 * c0 + 16) ^ m)) = hi;
    }
}

// ---- attn12: split-K across blocks, 3-buf LDS, prefetch-2, ONE barrier/iter ----
__global__ __launch_bounds__(512, 4) void attn12(const float* __restrict__ Q,
                                                 const unsigned short* __restrict__ ws,
                                                 float* __restrict__ O,
                                                 char* __restrict__ wsc)
{
    __shared__ __align__(16) char lds[3][TILE_BYTES];   // 48 KB

    const int tid  = threadIdx.x;
    const int lane = tid & 63;
    const int w    = tid >> 6;        // wave 0..7
    const int lq   = lane & 15;
    const int g    = lane >> 4;

    const int bid = blockIdx.x;
    const int bh  = bid & 31;         // XCD bh%8 == prep's XCD
    const int mc  = bid >> 5;         // 0..15
    const int m   = 7 - (mc >> 1);    // group desc: longest first
    const int c   = mc & 1;           // kv chunk
    const int b0  = bh >> 3, h = bh & 7;

    const int q0  = m * 256 + w * 32;
    const int kb  = c ? (2 * m + 2) : 0;
    const int ke  = c ? (4 * m + 4) : (2 * m + 2);
    const int dkt = 4 * m + (w >> 1);
    int qrow[2];
    qrow[0] = q0 + lq;
    qrow[1] = q0 + 16 + lq;

    bf16x8 qf[2][2];
    #pragma unroll
    for (int qs = 0; qs < 2; ++qs) {
        const float* qptr = Q + (((size_t)(b0 * L_ + qrow[qs])) * H_ + h) * E_;
        #pragma unroll
        for (int eb = 0; eb < 2; ++eb) {
            const float* pq = qptr + eb * 32 + g * 8;
            f32x4 a = *(const f32x4*)pq;
            f32x4 b = *(const f32x4*)(pq + 4);
            bf16x8 qv;
            #pragma unroll
            for (int k = 0; k < 4; ++k) {
                qv[k]     = (short)f2bf(a[k] * SCL);
                qv[4 + k] = (short)f2bf(b[k] * SCL);
            }
            qf[qs][eb] = qv;
        }
    }

    f32x4 acc[2][4] = {};
    float ls[2] = {0.f, 0.f};

    const char* tb = (const char*)ws + (size_t)bh * NT_ * TILE_BYTES;

    // prologue: stage tiles kb, kb+1 into bufs 0,1
    {
        const char* gp = tb + (size_t)kb * TILE_BYTES;
        gload16(gp + tid * 16, &lds[0][tid * 16]);
        gload16(gp + 8192 + tid * 16, &lds[0][8192 + tid * 16]);
        if (kb + 1 < ke) {
            gp += TILE_BYTES;
            gload16(gp + tid * 16, &lds[1][tid * 16]);
            gload16(gp + 8192 + tid * 16, &lds[1][8192 + tid * 16]);
        }
    }

    int buf = 0;
    for (int kt = kb; kt < ke; ++kt) {
        if (kt + 1 < ke) asm volatile("s_waitcnt vmcnt(2)" ::: "memory");
        else             asm volatile("s_waitcnt vmcnt(0)" ::: "memory");
        __builtin_amdgcn_s_barrier();      // tile kt visible AND all waves done with buf being restaged
        __builtin_amdgcn_sched_barrier(0);

        if (kt + 2 < ke) {                 // stage kt+2 into the buffer freed at the barrier
            const int nb = (buf + 2 == 3) ? 2 : (buf + 2 - 3 >= 0 ? buf - 1 : buf + 2);
            char* lp = &lds[(buf + 2) % 3][0];
            (void)nb;
            const char* gp = tb + (size_t)(kt + 2) * TILE_BYTES;
            gload16(gp + tid * 16, lp + tid * 16);
            gload16(gp + 8192 + tid * 16, lp + 8192 + tid * 16);
        }

        if (kt <= dkt) {
            const char* Kl = &lds[buf][0];
            const char* Vl = &lds[buf][8192];
            const int kv0 = kt * 64;

            u32x4 pw[2][2];
            #pragma unroll
            for (int st = 0; st < 4; ++st) {
                const int row = st * 16 + lq;
                const int mm = (row & 7) << 4;
                const char* kr = Kl + row * 128;
                bf16x8 k0 = *(const bf16x8*)(kr + ((16 * g) ^ mm));
                bf16x8 k1 = *(const bf16x8*)(kr + ((64 + 16 * g) ^ mm));
                #pragma unroll
                for (int qs = 0; qs < 2; ++qs) {
                    f32x4 z = {0.f, 0.f, 0.f, 0.f};
                    __builtin_amdgcn_s_setprio(1);
                    f32x4 cc = __builtin_amdgcn_mfma_f32_16x16x32_bf16(k0, qf[qs][0], z, 0, 0, 0);
                    cc = __builtin_amdgcn_mfma_f32_16x16x32_bf16(k1, qf[qs][1], cc, 0, 0, 0);
                    __builtin_amdgcn_s_setprio(0);
                    if (kt == dkt) {
                        #pragma unroll
                        for (int r = 0; r < 4; ++r) {
                            const int kv = kv0 + 32 * (st >> 1) + 8 * g + 4 * (st & 1) + r;
                            if (kv > qrow[qs]) cc[r] = -INFINITY;
                        }
                    }
                    f32x4 ev;
                    #pragma unroll
                    for (int r = 0; r < 4; ++r)
                        asm("v_exp_f32 %0, %1" : "=v"(ev[r]) : "v"(cc[r]));
                    ls[qs] += (ev[0] + ev[1]) + (ev[2] + ev[3]);
                    asm("v_cvt_pk_bf16_f32 %0, %1, %2" : "=v"(pw[qs][st >> 1][2 * (st & 1)])     : "v"(ev[0]), "v"(ev[1]));
                    asm("v_cvt_pk_bf16_f32 %0, %1, %2" : "=v"(pw[qs][st >> 1][2 * (st & 1) + 1]) : "v"(ev[2]), "v"(ev[3]));
                }
            }

            #pragma unroll
            for (int dt = 0; dt < 4; ++dt) {
                const int row = dt * 16 + lq;
                const int mm = (row & 7) << 4;
                bf16x8 v0 = *(const bf16x8*)(Vl + row * 128 + ((16 * g) ^ mm));
                bf16x8 v1 = *(const bf16x8*)(Vl + row * 128 + ((64 + 16 * g) ^ mm));
                __builtin_amdgcn_s_setprio(1);
                #pragma unroll
                for (int qs = 0; qs < 2; ++qs) {
                    acc[qs][dt] = __builtin_amdgcn_mfma_f32_16x16x32_bf16(v0, __builtin_bit_cast(bf16x8, pw[qs][0]), acc[qs][dt], 0, 0, 0);
                    acc[qs][dt] = __builtin_amdgcn_mfma_f32_16x16x32_bf16(v1, __builtin_bit_cast(bf16x8, pw[qs][1]), acc[qs][dt], 0, 0, 0);
                }
                __builtin_amdgcn_s_setprio(0);
            }
        }
        buf = (buf + 1) % 3;
    }

    // epilogue: chunk 0 raw f32 -> O; chunk 1 raw bf16 -> ws P1; l -> ws arrays
    float* lc = (float*)(wsc + (c ? L1_OFF : L0_OFF));
    #pragma unroll
    for (int qs = 0; qs < 2; ++qs) {
        float l = ls[qs] + __shfl_xor(ls[qs], 16);
        l += __shfl_xor(l, 32);
        if (lane < 16) lc[bh * L_ + qrow[qs]] = l;
        const size_t obase = (((size_t)(b0 * L_ + qrow[qs])) * H_ + h) * D_;
        if (c == 0) {
            float* op = O + obase;
            #pragma unroll
            for (int dt = 0; dt < 4; ++dt)
                *(f32x4*)(op + dt * 16 + 4 * g) = acc[qs][dt];
        } else {
            unsigned short* pp = (unsigned short*)(wsc + P1_OFF) + obase;
            #pragma unroll
            for (int dt = 0; dt < 4; ++dt) {
                unsigned int w0, w1;
                asm("v_cvt_pk_bf16_f32 %0, %1, %2" : "=v"(w0) : "v"(acc[qs][dt][0]), "v"(acc[qs][dt][1]));
                asm("v_cvt_pk_bf16_f32 %0, %1, %2" : "=v"(w1) : "v"(acc[qs][dt][2]), "v"(acc[qs][dt][3]));
                *(uint2*)(pp + dt * 16 + 4 * g) = make_uint2(w0, w1);
            }
        }
    }
}

// ---------------- combine: O = (P0 + P1bf16) / (l0 + l1) ----------------
__global__ __launch_bounds__(256) void combine12(float* __restrict__ O,
                                                 const char* __restrict__ wsc)
{
    const unsigned short* P1 = (const unsigned short*)(wsc + P1_OFF);
    const float* l0 = (const float*)(wsc + L0_OFF);
    const float* l1 = (const float*)(wsc + L1_OFF);
    const int f = (blockIdx.x * 256 + threadIdx.x) * 8;
    const int h = (f >> 6) & 7;
    const int l = (f >> 9) & (L_ - 1);
    const int b = f >> 20;
    const int li = (b * 8 + h) * L_ + l;
    const float inv = 1.0f / (l0[li] + l1[li]);
    f32x4 a0 = *(f32x4*)(O + f);
    f32x4 a1 = *(f32x4*)(O + f + 4);
    u16x8 pb = *(const u16x8*)(P1 + f);
    #pragma unroll
    for (int r = 0; r < 4; ++r) {
        a0[r] = (a0[r] + __builtin_bit_cast(float, (unsigned)pb[r] << 16)) * inv;
        a1[r] = (a1[r] + __builtin_bit_cast(float, (unsigned)pb[4 + r] << 16)) * inv;
    }
    *(f32x4*)(O + f)     = a0;
    *(f32x4*)(O + f + 4) = a1;
}

// ---- attn11 (round-11 proven): fallback for mid-size ws ----
#define STAGE2(I, BUF) do { \
    const char* sa = tb + (size_t)(I) * TILE_BYTES; \
    const char* sb = tb + (size_t)(jj + 1 + (I)) * TILE_BYTES; \
    char* da = pool + (BUF) * 16384 + tid * 16; \
    char* db = pool + 32768 + (BUF) * 16384 + tid * 16; \
    gload16(sa + tid * 16, da); \
    gload16(sa + 8192 + tid * 16, da + 8192); \
    gload16(sb + tid * 16, db); \
    gload16(sb + 8192 + tid * 16, db + 8192); \
} while (0)

__global__ __launch_bounds__(512, 4) void attn11(const float* __restrict__ Q,
                                                 const unsigned short* __restrict__ ws,
                                                 float* __restrict__ O)
{
    __shared__ __align__(16) char pool[65536];
    const int tid  = threadIdx.x;
    const int lane = tid & 63;
    const int w    = tid >> 6;
    const int team = w >> 2;
    const int tw   = w & 3;
    const int lq   = lane & 15;
    const int g    = lane >> 4;
    const int bid = blockIdx.x;
    const int bh  = bid & 31;
    const int q   = bid >> 5;
    const int jj  = (q < 8) ? (15 - q) : (q - 8);
    const int b0  = bh >> 3, h = bh & 7;
    const int q0 = jj * 128 + tw * 32;
    int qrow[2];
    qrow[0] = q0 + lq;
    qrow[1] = q0 + 16 + lq;
    const int dktB = 2 * jj + (tw >> 1);
    bf16x8 qf[2][2];
    #pragma unroll
    for (int qs = 0; qs < 2; ++qs) {
        const float* qptr = Q + (((size_t)(b0 * L_ + qrow[qs])) * H_ + h) * E_;
        #pragma unroll
        for (int eb = 0; eb < 2; ++eb) {
            const float* pq = qptr + eb * 32 + g * 8;
            f32x4 a = *(const f32x4*)pq;
            f32x4 b = *(const f32x4*)(pq + 4);
            bf16x8 qv;
            #pragma unroll
            for (int k = 0; k < 4; ++k) {
                qv[k]     = (short)f2bf(a[k] * SCL);
                qv[4 + k] = (short)f2bf(b[k] * SCL);
            }
            qf[qs][eb] = qv;
        }
    }
    f32x4 acc[2][4] = {};
    float ls[2] = {0.f, 0.f};
    const char* tb = (const char*)ws + (size_t)bh * NT_ * TILE_BYTES;
    STAGE2(0, 0);
    int cur = 0;
    for (int i = 0; i <= jj; ++i) {
        if (i < jj) {
            STAGE2(i + 1, cur ^ 1);
            asm volatile("s_waitcnt vmcnt(4)" ::: "memory");
        } else {
            asm volatile("s_waitcnt vmcnt(0)" ::: "memory");
        }
        __builtin_amdgcn_s_barrier();
        __builtin_amdgcn_sched_barrier(0);
        const int kt = team ? (jj + 1 + i) : i;
        const bool active = (team == 0) || (kt <= dktB);
        if (active) {
            const char* Kl = pool + team * 32768 + cur * 16384;
            const char* Vl = Kl + 8192;
            const int kv0 = kt * 64;
            const bool maskit = (kt >= 2 * jj);
            u32x4 pw[2][2];
            #pragma unroll
            for (int st = 0; st < 4; ++st) {
                const int row = st * 16 + lq;
                const int mm = (row & 7) << 4;
                const char* kr = Kl + row * 128;
                bf16x8 k0 = *(const bf16x8*)(kr + ((16 * g) ^ mm));
                bf16x8 k1 = *(const bf16x8*)(kr + ((64 + 16 * g) ^ mm));
                #pragma unroll
                for (int qs = 0; qs < 2; ++qs) {
                    f32x4 z = {0.f, 0.f, 0.f, 0.f};
                    __builtin_amdgcn_s_setprio(1);
                    f32x4 cc = __builtin_amdgcn_mfma_f32_16x16x32_bf16(k0, qf[qs][0], z, 0, 0, 0);
                    cc = __builtin_amdgcn_mfma_f32_16x16x32_bf16(k1, qf[qs][1], cc, 0, 0, 0);
                    __builtin_amdgcn_s_setprio(0);
                    if (maskit) {
                        #pragma unroll
                        for (int r = 0; r < 4; ++r) {
                            const int kv = kv0 + 32 * (st >> 1) + 8 * g + 4 * (st & 1) + r;
                            if (kv > qrow[qs]) cc[r] = -INFINITY;
                        }
                    }
                    f32x4 ev;
                    #pragma unroll
                    for (int r = 0; r < 4; ++r)
                        asm("v_exp_f32 %0, %1" : "=v"(ev[r]) : "v"(cc[r]));
                    ls[qs] += (ev[0] + ev[1]) + (ev[2] + ev[3]);
                    asm("v_cvt_pk_bf16_f32 %0, %1, %2" : "=v"(pw[qs][st >> 1][2 * (st & 1)])     : "v"(ev[0]), "v"(ev[1]));
                    asm("v_cvt_pk_bf16_f32 %0, %1, %2" : "=v"(pw[qs][st >> 1][2 * (st & 1) + 1]) : "v"(ev[2]), "v"(ev[3]));
                }
            }
            #pragma unroll
            for (int dt = 0; dt < 4; ++dt) {
                const int row = dt * 16 + lq;
                const int mm = (row & 7) << 4;
                bf16x8 v0 = *(const bf16x8*)(Vl + row * 128 + ((16 * g) ^ mm));
                bf16x8 v1 = *(const bf16x8*)(Vl + row * 128 + ((64 + 16 * g) ^ mm));
                __builtin_amdgcn_s_setprio(1);
                #pragma unroll
                for (int qs = 0; qs < 2; ++qs) {
                    acc[qs][dt] = __builtin_amdgcn_mfma_f32_16x16x32_bf16(v0, __builtin_bit_cast(bf16x8, pw[qs][0]), acc[qs][dt], 0, 0, 0);
                    acc[qs][dt] = __builtin_amdgcn_mfma_f32_16x16x32_bf16(v1, __builtin_bit_cast(bf16x8, pw[qs][1]), acc[qs][dt], 0, 0, 0);
                }
                __builtin_amdgcn_s_setprio(0);
            }
        }
        __builtin_amdgcn_s_barrier();
        cur ^= 1;
    }
    __builtin_amdgcn_s_barrier();
    float* sacc = (float*)pool;
    float* sls  = (float*)(pool + 128 * 68 * 4);
    if (team == 1) {
        #pragma unroll
        for (int qs = 0; qs < 2; ++qs) {
            const int rowl = 32 * tw + 16 * qs + lq;
            float l = ls[qs] + __shfl_xor(ls[qs], 16);
            l += __shfl_xor(l, 32);
            if (g == 0) sls[rowl] = l;
            #pragma unroll
            for (int dt = 0; dt < 4; ++dt)
                *(f32x4*)&sacc[rowl * 68 + dt * 16 + 4 * g] = acc[qs][dt];
        }
    }
    __syncthreads();
    if (team == 0) {
        #pragma unroll
        for (int qs = 0; qs < 2; ++qs) {
            const int rowl = 32 * tw + 16 * qs + lq;
            float l = ls[qs] + __shfl_xor(ls[qs], 16);
            l += __shfl_xor(l, 32);
            const float inv = 1.0f / (l + sls[rowl]);
            float* op = O + (((size_t)(b0 * L_ + qrow[qs])) * H_ + h) * D_;
            #pragma unroll
            for (int dt = 0; dt < 4; ++dt) {
                f32x4 p = *(const f32x4*)&sacc[rowl * 68 + dt * 16 + 4 * g];
                f32x4 o;
                #pragma unroll
                for (int r = 0; r < 4; ++r) o[r] = (acc[qs][dt][r] + p[r]) * inv;
                *(f32x4*)(op + dt * 16 + 4 * g) = o;
            }
        }
    }
}

// ---------------- fallback (round-1 kernel, proven) for tiny ws ----------------
#define KPITCH 72
__global__ __launch_bounds__(256, 2) void attn_fwd_fb(
    const float* __restrict__ Q, const float* __restrict__ K,
    const float* __restrict__ V, float* __restrict__ O)
{
    __shared__ unsigned short Klds[64 * KPITCH];
    __shared__ unsigned short Vlds[64 * KPITCH];
    const int tid = threadIdx.x, lane = tid & 63, w = tid >> 6;
    const int lq = lane & 15, g = lane >> 4;
    const int bid = blockIdx.x, qb = bid & 31, bh = bid >> 5;
    const int b0 = bh >> 3, h = bh & 7;
    const int q0 = qb * 64, qrow = q0 + w * 16 + lq;
    const float* qptr = Q + ((size_t)(b0 * L_ + qrow) * H_ + h) * E_;
    bf16x8 qf[2];
    #pragma unroll
    for (int eb = 0; eb < 2; ++eb) {
        const float* pp = qptr + eb * 32 + g * 8;
        f32x4 a = *(const f32x4*)pp; f32x4 b = *(const f32x4*)(pp + 4);
        bf16x8 qv;
        #pragma unroll
        for (int jq = 0; jq < 4; ++jq) { qv[jq] = (short)f2bf(a[jq] * 0.125f); qv[4 + jq] = (short)f2bf(b[jq] * 0.125f); }
        qf[eb] = qv;
    }
    const int tr = tid >> 2, tc = tid & 3;
    const int rh = rho(tr);
    f32x4 acc[4] = {};
    float mrow = -INFINITY, lrow = 0.f;
    for (int kt = 0; kt < qb + 1; ++kt) {
        const int kv0 = kt * 64;
        __syncthreads();
        {
            const float* krow = K + ((size_t)((b0 * S_ + kv0 + tr)) * H_ + h) * E_;
            const float* vrow = V + ((size_t)((b0 * S_ + kv0 + tr)) * H_ + h) * D_;
            #pragma unroll
            for (int i = 0; i < 4; ++i) {
                const int e0 = tc * 4 + i * 16;
                f32x4 k4 = *(const f32x4*)(krow + e0);
                unsigned int lo = (unsigned)f2bf(k4[0]) | ((unsigned)f2bf(k4[1]) << 16);
                unsigned int hi = (unsigned)f2bf(k4[2]) | ((unsigned)f2bf(k4[3]) << 16);
                *(uint2*)&Klds[rh * KPITCH + e0] = make_uint2(lo, hi);
                f32x4 v4 = *(const f32x4*)(vrow + e0);
                #pragma unroll
                for (int k2 = 0; k2 < 4; ++k2) Vlds[(e0 + k2) * KPITCH + tr] = f2bf(v4[k2]);
            }
        }
        __syncthreads();
        f32x4 sc[4];
        #pragma unroll
        for (int st = 0; st < 4; ++st) {
            const unsigned short* kr = &Klds[(st * 16 + lq) * KPITCH];
            bf16x8 ka0 = *(const bf16x8*)(kr + 8 * g);
            bf16x8 ka1 = *(const bf16x8*)(kr + 32 + 8 * g);
            f32x4 cc = {0.f, 0.f, 0.f, 0.f};
            cc = __builtin_amdgcn_mfma_f32_16x16x32_bf16(ka0, qf[0], cc, 0, 0, 0);
            cc = __builtin_amdgcn_mfma_f32_16x16x32_bf16(ka1, qf[1], cc, 0, 0, 0);
            sc[st] = cc;
        }
        float tmax = -INFINITY;
        #pragma unroll
        for (int st = 0; st < 4; ++st) {
            const int kvb = kv0 + 32 * (st >> 1) + 8 * g + 4 * (st & 1);
            #pragma unroll
            for (int r = 0; r < 4; ++r) { if (kvb + r > qrow) sc[st][r] = -INFINITY; tmax = fmaxf(tmax, sc[st][r]); }
        }
        tmax = fmaxf(tmax, __shfl_xor(tmax, 16));
        tmax = fmaxf(tmax, __shfl_xor(tmax, 32));
        const float mnew = fmaxf(mrow, tmax);
        const float corr = __expf(mrow - mnew);
        float pv[4][4]; float tsum = 0.f;
        #pragma unroll
        for (int st = 0; st < 4; ++st)
            #pragma unroll
            for (int r = 0; r < 4; ++r) { float e = __expf(sc[st][r] - mnew); pv[st][r] = e; tsum += e; }
        tsum += __shfl_xor(tsum, 16); tsum += __shfl_xor(tsum, 32);
        lrow = lrow * corr + tsum; mrow = mnew;
        #pragma unroll
        for (int dt = 0; dt < 4; ++dt)
            #pragma unroll
            for (int r = 0; r < 4; ++r) acc[dt][r] *= corr;
        bf16x8 pb[2];
        #pragma unroll
        for (int bb = 0; bb < 2; ++bb)
            #pragma unroll
            for (int s = 0; s < 2; ++s)
                #pragma unroll
                for (int r = 0; r < 4; ++r) pb[bb][4 * s + r] = (short)f2bf(pv[2 * bb + s][r]);
        #pragma unroll
        for (int bb = 0; bb < 2; ++bb)
            #pragma unroll
            for (int dt = 0; dt < 4; ++dt) {
                bf16x8 va = *(const bf16x8*)&Vlds[(dt * 16 + lq) * KPITCH + 32 * bb + 8 * g];
                acc[dt] = __builtin_amdgcn_mfma_f32_16x16x32_bf16(va, pb[bb], acc[dt], 0, 0, 0);
            }
    }
    const float inv = 1.0f / lrow;
    float* optr = O + ((size_t)(b0 * L_ + qrow) * H_ + h) * D_;
    #pragma unroll
    for (int dt = 0; dt < 4; ++dt) {
        f32x4 o;
        #pragma unroll
        for (int r = 0; r < 4; ++r) o[r] = acc[dt][r] * inv;
        *(f32x4*)(optr + dt * 16 + 4 * g) = o;
    }
}

extern "C" void kernel_launch(void* const* d_in, const int* in_sizes, int n_in,
                              void* d_out, int out_size, void* d_ws, size_t ws_size,
                              hipStream_t stream) {
    const float* Q = (const float*)d_in[0];
    const float* K = (const float*)d_in[1];
    const float* V = (const float*)d_in[2];
    float* O = (float*)d_out;
    if (ws_size >= WS2_NEEDED) {
        prep_kv<<<dim3(B_ * H_ * NT_), 256, 0, stream>>>(K, V, (unsigned short*)d_ws);
        attn12<<<dim3(512), 512, 0, stream>>>(Q, (const unsigned short*)d_ws, O, (char*)d_ws);
        combine12<<<dim3(2048), 256, 0, stream>>>(O, (const char*)d_ws);
    } else if (ws_size >= WS_NEEDED) {
        prep_kv<<<dim3(B_ * H_ * NT_), 256, 0, stream>>>(K, V, (unsigned short*)d_ws);
        attn11<<<dim3(512), 512, 0, stream>>>(Q, (const unsigned short*)d_ws, O);
    } else {
        attn_fwd_fb<<<dim3(B_ * H_ * 32), 256, 0, stream>>>(Q, K, V, O);
    }
}

// Round 13
// 43.941 us; speedup vs baseline: 1.1868x; 1.1868x over previous
//
#include <hip/hip_runtime.h>
#include <math.h>

typedef __attribute__((ext_vector_type(8))) short bf16x8;
typedef __attribute__((ext_vector_type(4))) float f32x4;
typedef __attribute__((ext_vector_type(4))) unsigned int u32x4;

#define B_ 4
#define L_ 2048
#define S_ 2048
#define H_ 8
#define E_ 64
#define D_ 64
#define NT_ 32
#define TILE_BYTES 16384
#define WS_NEEDED ((size_t)B_ * H_ * NT_ * TILE_BYTES)   // 16 MB tile images
#define SCL (0.125f * 1.44269504088896f)                  // 1/sqrt(E) * log2(e)

__device__ __forceinline__ unsigned short f2bf(float x) {
    unsigned int u = __builtin_bit_cast(unsigned int, x);
    u += 0x7fffu + ((u >> 16) & 1u);
    return (unsigned short)(u >> 16);
}
// kv-row permute so S^T C-fragment layout == PV A-operand layout (verified rounds 1-12)
__device__ __forceinline__ int rho(int r) {
    return (r & 32) | (((r >> 2) & 1) << 4) | (((r >> 3) & 3) << 2) | (r & 3);
}
__device__ __forceinline__ void gload16(const void* g, void* l) {
    __builtin_amdgcn_global_load_lds((const __attribute__((address_space(1))) unsigned int*)g,
                                     (__attribute__((address_space(3))) unsigned int*)l, 16, 0, 0);
}

// ---------------- prep: K -> bf16 tile image, V -> V^T image; XCD-aligned to consumer ----------------
__global__ __launch_bounds__(256) void prep_kv(const float* __restrict__ K,
                                               const float* __restrict__ V,
                                               unsigned short* __restrict__ ws)
{
    __shared__ __align__(16) unsigned short vt[64][80];
    const int tid = threadIdx.x;
    const int bid = blockIdx.x;
    const int kt  = bid >> 5;
    const int bh  = (((bid >> 3) & 3) << 3) | (bid & 7);      // bid%8 == bh%8
    const int b   = bh >> 3, h = bh & 7;
    const int s0  = kt * 64;
    const int r   = tid >> 2;
    const int e0  = (tid & 3) * 16;

    const float* krow = K + (((size_t)(b * S_ + s0 + r)) * H_ + h) * E_ + e0;
    const float* vrow = V + (((size_t)(b * S_ + s0 + r)) * H_ + h) * D_ + e0;
    char* tile = (char*)(ws) + ((size_t)(bh * NT_ + kt) * TILE_BYTES);

    unsigned short kb[16];
    #pragma unroll
    for (int i = 0; i < 4; ++i) {
        f32x4 k4 = *(const f32x4*)(krow + i * 4);
        #pragma unroll
        for (int jq = 0; jq < 4; ++jq) kb[i * 4 + jq] = f2bf(k4[jq]);
    }
    {
        const int rr = rho(r);
        const int m  = (rr & 7) << 4;
        char* kbase = tile + rr * 128;
        u32x4 lo, hi;
        #pragma unroll
        for (int jq = 0; jq < 4; ++jq) {
            lo[jq] = (unsigned)kb[2 * jq] | ((unsigned)kb[2 * jq + 1] << 16);
            hi[jq] = (unsigned)kb[8 + 2 * jq] | ((unsigned)kb[9 + 2 * jq] << 16);
        }
        *(u32x4*)(kbase + ((2 * e0) ^ m))      = lo;
        *(u32x4*)(kbase + ((2 * e0 + 16) ^ m)) = hi;
    }
    #pragma unroll
    for (int i = 0; i < 4; ++i) {
        f32x4 v4 = *(const f32x4*)(vrow + i * 4);
        #pragma unroll
        for (int jq = 0; jq < 4; ++jq) vt[e0 + i * 4 + jq][r] = f2bf(v4[jq]);
    }
    __syncthreads();
    {
        const int d  = tid >> 2;
        const int c0 = (tid & 3) * 16;
        const int m  = (d & 7) << 4;
        char* vbase = tile + 8192 + d * 128;
        u32x4 lo = *(const u32x4*)&vt[d][c0];
        u32x4 hi = *(const u32x4*)&vt[d][c0 + 8];
        *(u32x4*)(vbase + ((2 * c0) ^ m))      = lo;
        *(u32x4*)(vbase + ((2 * c0 + 16) ^ m)) = hi;
    }
}

// ---- attn13: per-block split-K (2 teams x 2 waves) on one 64-row group; two groups/block ----
// pool layout during loop: [teamA buf0 16K][teamA buf1 16K][teamB buf0 16K][teamB buf1 16K]
// pool layout during combine: float sacc[64][68] (17408 B) + float sls[64]
__device__ __forceinline__ void do_group(
    const float* __restrict__ Q, const char* __restrict__ tb, char* __restrict__ pool,
    int b0, int h, int g, int team, int tw, int lq, int gl, int tid,
    float* __restrict__ O)
{
    const int nt = g + 1;
    const int nh = (nt + 1) >> 1;                 // team A iters; team B covers [nh, nt)
    const int q0 = g * 64 + tw * 32;
    int qrow[2];
    qrow[0] = q0 + lq;
    qrow[1] = q0 + 16 + lq;

    // Q fragments (B-operand), scale*log2e folded => scores in exp2 domain
    bf16x8 qf[2][2];
    #pragma unroll
    for (int qs = 0; qs < 2; ++qs) {
        const float* qptr = Q + (((size_t)(b0 * L_ + qrow[qs])) * H_ + h) * E_;
        #pragma unroll
        for (int eb = 0; eb < 2; ++eb) {
            const float* pq = qptr + eb * 32 + gl * 8;
            f32x4 a = *(const f32x4*)pq;
            f32x4 b = *(const f32x4*)(pq + 4);
            bf16x8 qv;
            #pragma unroll
            for (int k = 0; k < 4; ++k) {
                qv[k]     = (short)f2bf(a[k] * SCL);
                qv[4 + k] = (short)f2bf(b[k] * SCL);
            }
            qf[qs][eb] = qv;
        }
    }

    f32x4 acc[2][4] = {};
    float ls[2] = {0.f, 0.f};

    // stage tile pair (A tile i, B tile nh+i clamped) into buf
    #define STAGE13(I, BUF) do { \
        int tbi = nh + (I); if (tbi > nt - 1) tbi = nt - 1; \
        const char* ga = tb + (size_t)(I) * TILE_BYTES; \
        const char* gb = tb + (size_t)tbi * TILE_BYTES; \
        char* la = pool + (BUF) * 16384; \
        char* lb = pool + 32768 + (BUF) * 16384; \
        _Pragma("unroll") \
        for (int r4 = 0; r4 < 4; ++r4) { \
            gload16(ga + r4 * 4096 + tid * 16, la + r4 * 4096 + tid * 16); \
            gload16(gb + r4 * 4096 + tid * 16, lb + r4 * 4096 + tid * 16); \
        } \
    } while (0)

    STAGE13(0, 0);
    int cur = 0;
    for (int i = 0; i < nh; ++i) {
        if (i + 1 < nh) {
            STAGE13(i + 1, cur ^ 1);
            asm volatile("s_waitcnt vmcnt(8)" ::: "memory");
        } else {
            asm volatile("s_waitcnt vmcnt(0)" ::: "memory");
        }
        __builtin_amdgcn_s_barrier();
        __builtin_amdgcn_sched_barrier(0);

        const int kt = team ? (nh + i) : i;
        const bool active = team ? (kt < nt) : true;
        if (active) {
            const char* Kl = pool + team * 32768 + cur * 16384;
            const char* Vl = Kl + 8192;
            const int kv0 = kt * 64;
            const bool maskit = (kt == g);

            u32x4 pw[2][2];
            #pragma unroll
            for (int st = 0; st < 4; ++st) {
                const int row = st * 16 + lq;
                const int mm = (row & 7) << 4;
                const char* kr = Kl + row * 128;
                bf16x8 k0 = *(const bf16x8*)(kr + ((16 * gl) ^ mm));
                bf16x8 k1 = *(const bf16x8*)(kr + ((64 + 16 * gl) ^ mm));
                #pragma unroll
                for (int qs = 0; qs < 2; ++qs) {
                    f32x4 z = {0.f, 0.f, 0.f, 0.f};
                    __builtin_amdgcn_s_setprio(1);
                    f32x4 cc = __builtin_amdgcn_mfma_f32_16x16x32_bf16(k0, qf[qs][0], z, 0, 0, 0);
                    cc = __builtin_amdgcn_mfma_f32_16x16x32_bf16(k1, qf[qs][1], cc, 0, 0, 0);
                    __builtin_amdgcn_s_setprio(0);
                    if (maskit) {
                        #pragma unroll
                        for (int r = 0; r < 4; ++r) {
                            const int kv = kv0 + 32 * (st >> 1) + 8 * gl + 4 * (st & 1) + r;
                            if (kv > qrow[qs]) cc[r] = -INFINITY;
                        }
                    }
                    f32x4 ev;
                    #pragma unroll
                    for (int r = 0; r < 4; ++r)
                        asm("v_exp_f32 %0, %1" : "=v"(ev[r]) : "v"(cc[r]));
                    ls[qs] += (ev[0] + ev[1]) + (ev[2] + ev[3]);
                    asm("v_cvt_pk_bf16_f32 %0, %1, %2" : "=v"(pw[qs][st >> 1][2 * (st & 1)])     : "v"(ev[0]), "v"(ev[1]));
                    asm("v_cvt_pk_bf16_f32 %0, %1, %2" : "=v"(pw[qs][st >> 1][2 * (st & 1) + 1]) : "v"(ev[2]), "v"(ev[3]));
                }
            }

            #pragma unroll
            for (int dt = 0; dt < 4; ++dt) {
                const int row = dt * 16 + lq;
                const int mm = (row & 7) << 4;
                bf16x8 v0 = *(const bf16x8*)(Vl + row * 128 + ((16 * gl) ^ mm));
                bf16x8 v1 = *(const bf16x8*)(Vl + row * 128 + ((64 + 16 * gl) ^ mm));
                __builtin_amdgcn_s_setprio(1);
                #pragma unroll
                for (int qs = 0; qs < 2; ++qs) {
                    acc[qs][dt] = __builtin_amdgcn_mfma_f32_16x16x32_bf16(v0, __builtin_bit_cast(bf16x8, pw[qs][0]), acc[qs][dt], 0, 0, 0);
                    acc[qs][dt] = __builtin_amdgcn_mfma_f32_16x16x32_bf16(v1, __builtin_bit_cast(bf16x8, pw[qs][1]), acc[qs][dt], 0, 0, 0);
                }
                __builtin_amdgcn_s_setprio(0);
            }
        }
        __builtin_amdgcn_s_barrier();
        cur ^= 1;
    }
    #undef STAGE13

    // ---- in-block combine (tile buffers are dead; alias pool) ----
    float* sacc = (float*)pool;                   // [64][68]
    float* sls  = (float*)(pool + 64 * 68 * 4);   // [64]
    if (team == 1) {
        #pragma unroll
        for (int qs = 0; qs < 2; ++qs) {
            const int rowl = tw * 32 + qs * 16 + lq;
            float l = ls[qs] + __shfl_xor(ls[qs], 16);
            l += __shfl_xor(l, 32);
            if (gl == 0) sls[rowl] = l;
            #pragma unroll
            for (int dt = 0; dt < 4; ++dt)
                *(f32x4*)&sacc[rowl * 68 + dt * 16 + 4 * gl] = acc[qs][dt];
        }
    }
    __syncthreads();
    if (team == 0) {
        #pragma unroll
        for (int qs = 0; qs < 2; ++qs) {
            const int rowl = tw * 32 + qs * 16 + lq;
            float l = ls[qs] + __shfl_xor(ls[qs], 16);
            l += __shfl_xor(l, 32);
            const float inv = 1.0f / (l + sls[rowl]);
            float* op = O + (((size_t)(b0 * L_ + qrow[qs])) * H_ + h) * D_;
            #pragma unroll
            for (int dt = 0; dt < 4; ++dt) {
                f32x4 p = *(const f32x4*)&sacc[rowl * 68 + dt * 16 + 4 * gl];
                f32x4 o;
                #pragma unroll
                for (int r = 0; r < 4; ++r) o[r] = (acc[qs][dt][r] + p[r]) * inv;
                *(f32x4*)(op + dt * 16 + 4 * gl) = o;
            }
        }
    }
    __syncthreads();   // combine read done before pool is restaged by next phase
}

__global__ __launch_bounds__(256, 2) void attn13(const float* __restrict__ Q,
                                                 const unsigned short* __restrict__ ws,
                                                 float* __restrict__ O)
{
    __shared__ __align__(16) char pool[65536];

    const int tid  = threadIdx.x;
    const int lane = tid & 63;
    const int w    = tid >> 6;        // wave 0..3
    const int team = w >> 1;          // 0: kv [0,nh), 1: kv [nh,nt)
    const int tw   = w & 1;           // wave within team (32-row half of the 64-row group)
    const int lq   = lane & 15;
    const int gl   = lane >> 4;

    const int bid = blockIdx.x;
    const int bh  = bid & 31;         // XCD bh%8 == prep's XCD
    const int pr  = bid >> 5;         // 0..15
    const int b0  = bh >> 3, h = bh & 7;

    const char* tb = (const char*)ws + (size_t)bh * NT_ * TILE_BYTES;

    // two complementary 64-row groups: ceil((pr+1)/2)+ceil((32-pr)/2) == 17 iters, all blocks equal
    do_group(Q, tb, pool, b0, h, pr,      team, tw, lq, gl, tid, O);
    do_group(Q, tb, pool, b0, h, 31 - pr, team, tw, lq, gl, tid, O);
}

// ---------------- fallback (round-1 kernel, proven) for tiny ws ----------------
#define KPITCH 72
__global__ __launch_bounds__(256, 2) void attn_fwd_fb(
    const float* __restrict__ Q, const float* __restrict__ K,
    const float* __restrict__ V, float* __restrict__ O)
{
    __shared__ unsigned short Klds[64 * KPITCH];
    __shared__ unsigned short Vlds[64 * KPITCH];
    const int tid = threadIdx.x, lane = tid & 63, w = tid >> 6;
    const int lq = lane & 15, g = lane >> 4;
    const int bid = blockIdx.x, qb = bid & 31, bh = bid >> 5;
    const int b0 = bh >> 3, h = bh & 7;
    const int q0 = qb * 64, qrow = q0 + w * 16 + lq;
    const float* qptr = Q + ((size_t)(b0 * L_ + qrow) * H_ + h) * E_;
    bf16x8 qf[2];
    #pragma unroll
    for (int eb = 0; eb < 2; ++eb) {
        const float* pp = qptr + eb * 32 + g * 8;
        f32x4 a = *(const f32x4*)pp; f32x4 b = *(const f32x4*)(pp + 4);
        bf16x8 qv;
        #pragma unroll
        for (int jq = 0; jq < 4; ++jq) { qv[jq] = (short)f2bf(a[jq] * 0.125f); qv[4 + jq] = (short)f2bf(b[jq] * 0.125f); }
        qf[eb] = qv;
    }
    const int tr = tid >> 2, tc = tid & 3;
    const int rh = rho(tr);
    f32x4 acc[4] = {};
    float mrow = -INFINITY, lrow = 0.f;
    for (int kt = 0; kt < qb + 1; ++kt) {
        const int kv0 = kt * 64;
        __syncthreads();
        {
            const float* krow = K + ((size_t)((b0 * S_ + kv0 + tr)) * H_ + h) * E_;
            const float* vrow = V + ((size_t)((b0 * S_ + kv0 + tr)) * H_ + h) * D_;
            #pragma unroll
            for (int i = 0; i < 4; ++i) {
                const int e0 = tc * 4 + i * 16;
                f32x4 k4 = *(const f32x4*)(krow + e0);
                unsigned int lo = (unsigned)f2bf(k4[0]) | ((unsigned)f2bf(k4[1]) << 16);
                unsigned int hi = (unsigned)f2bf(k4[2]) | ((unsigned)f2bf(k4[3]) << 16);
                *(uint2*)&Klds[rh * KPITCH + e0] = make_uint2(lo, hi);
                f32x4 v4 = *(const f32x4*)(vrow + e0);
                #pragma unroll
                for (int k2 = 0; k2 < 4; ++k2) Vlds[(e0 + k2) * KPITCH + tr] = f2bf(v4[k2]);
            }
        }
        __syncthreads();
        f32x4 sc[4];
        #pragma unroll
        for (int st = 0; st < 4; ++st) {
            const unsigned short* kr = &Klds[(st * 16 + lq) * KPITCH];
            bf16x8 ka0 = *(const bf16x8*)(kr + 8 * g);
            bf16x8 ka1 = *(const bf16x8*)(kr + 32 + 8 * g);
            f32x4 cc = {0.f, 0.f, 0.f, 0.f};
            cc = __builtin_amdgcn_mfma_f32_16x16x32_bf16(ka0, qf[0], cc, 0, 0, 0);
            cc = __builtin_amdgcn_mfma_f32_16x16x32_bf16(ka1, qf[1], cc, 0, 0, 0);
            sc[st] = cc;
        }
        float tmax = -INFINITY;
        #pragma unroll
        for (int st = 0; st < 4; ++st) {
            const int kvb = kv0 + 32 * (st >> 1) + 8 * g + 4 * (st & 1);
            #pragma unroll
            for (int r = 0; r < 4; ++r) { if (kvb + r > qrow) sc[st][r] = -INFINITY; tmax = fmaxf(tmax, sc[st][r]); }
        }
        tmax = fmaxf(tmax, __shfl_xor(tmax, 16));
        tmax = fmaxf(tmax, __shfl_xor(tmax, 32));
        const float mnew = fmaxf(mrow, tmax);
        const float corr = __expf(mrow - mnew);
        float pv[4][4]; float tsum = 0.f;
        #pragma unroll
        for (int st = 0; st < 4; ++st)
            #pragma unroll
            for (int r = 0; r < 4; ++r) { float e = __expf(sc[st][r] - mnew); pv[st][r] = e; tsum += e; }
        tsum += __shfl_xor(tsum, 16); tsum += __shfl_xor(tsum, 32);
        lrow = lrow * corr + tsum; mrow = mnew;
        #pragma unroll
        for (int dt = 0; dt < 4; ++dt)
            #pragma unroll
            for (int r = 0; r < 4; ++r) acc[dt][r] *= corr;
        bf16x8 pb[2];
        #pragma unroll
        for (int bb = 0; bb < 2; ++bb)
            #pragma unroll
            for (int s = 0; s < 2; ++s)
                #pragma unroll
                for (int r = 0; r < 4; ++r) pb[bb][4 * s + r] = (short)f2bf(pv[2 * bb + s][r]);
        #pragma unroll
        for (int bb = 0; bb < 2; ++bb)
            #pragma unroll
            for (int dt = 0; dt < 4; ++dt) {
                bf16x8 va = *(const bf16x8*)&Vlds[(dt * 16 + lq) * KPITCH + 32 * bb + 8 * g];
                acc[dt] = __builtin_amdgcn_mfma_f32_16x16x32_bf16(va, pb[bb], acc[dt], 0, 0, 0);
            }
    }
    const float inv = 1.0f / lrow;
    float* optr = O + ((size_t)(b0 * L_ + qrow) * H_ + h) * D_;
    #pragma unroll
    for (int dt = 0; dt < 4; ++dt) {
        f32x4 o;
        #pragma unroll
        for (int r = 0; r < 4; ++r) o[r] = acc[dt][r] * inv;
        *(f32x4*)(optr + dt * 16 + 4 * g) = o;
    }
}

extern "C" void kernel_launch(void* const* d_in, const int* in_sizes, int n_in,
                              void* d_out, int out_size, void* d_ws, size_t ws_size,
                              hipStream_t stream) {
    const float* Q = (const float*)d_in[0];
    const float* K = (const float*)d_in[1];
    const float* V = (const float*)d_in[2];
    float* O = (float*)d_out;
    if (ws_size >= WS_NEEDED) {
        prep_kv<<<dim3(B_ * H_ * NT_), 256, 0, stream>>>(K, V, (unsigned short*)d_ws);
        attn13<<<dim3(512), 256, 0, stream>>>(Q, (const unsigned short*)d_ws, O);
    } else {
        attn_fwd_fb<<<dim3(B_ * H_ * 32), 256, 0, stream>>>(Q, K, V, O);
    }
}